// Round 1
// baseline (109.056 us; speedup 1.0000x reference)
//
#include <hip/hip_runtime.h>

// SqueezeSeg recurrent CRF, MI355X (gfx950).
// B=16, C=4, H=64, W=512, 3x5 stencil (14 neighbors), 3 iterations.
// Note: ANG_THETA_A == BILATERAL_THETA_A == 0.9 -> g_ang == g_bi -> ang == bi_ang.
// compat = (1 - I)*coef -> out[o] = coef*(sum_c v[c] - v[o]).

#define NCLASS 4
#define HH 64
#define WW 512
#define BB 16
#define TH 8
#define TW 128
#define HALO_H (TH + 2)
#define HALO_W (TW + 4)
#define PLANE (HH * WW)

__global__ __launch_bounds__(256) void crf_iter(
    const float* __restrict__ xin,   // [B,4,H,W]
    const float* __restrict__ filt,  // [B,1,14,H,W]
    const float* __restrict__ mask,  // [B,1,H,W]
    float* __restrict__ xout)        // [B,4,H,W]
{
    __shared__ float u_lds[NCLASS][HALO_H][HALO_W];
    __shared__ float m_lds[HALO_H][HALO_W];

    const int b  = blockIdx.z;
    const int h0 = blockIdx.y * TH;
    const int w0 = blockIdx.x * TW;
    const int tid = threadIdx.x;

    // ---- Phase 1: load halo tile, softmax over class dim into LDS ----
    for (int idx = tid; idx < HALO_H * HALO_W; idx += 256) {
        const int lr = idx / HALO_W;
        const int lc = idx - lr * HALO_W;
        const int gh = h0 + lr - 1;
        const int gw = w0 + lc - 2;
        if (gh >= 0 && gh < HH && gw >= 0 && gw < WW) {
            const int base = (b * NCLASS * HH + gh) * WW + gw;
            const float v0 = xin[base + 0 * PLANE];
            const float v1 = xin[base + 1 * PLANE];
            const float v2 = xin[base + 2 * PLANE];
            const float v3 = xin[base + 3 * PLANE];
            const float mx = fmaxf(fmaxf(v0, v1), fmaxf(v2, v3));
            const float e0 = expf(v0 - mx);
            const float e1 = expf(v1 - mx);
            const float e2 = expf(v2 - mx);
            const float e3 = expf(v3 - mx);
            const float inv = 1.0f / (e0 + e1 + e2 + e3);
            u_lds[0][lr][lc] = e0 * inv;
            u_lds[1][lr][lc] = e1 * inv;
            u_lds[2][lr][lc] = e2 * inv;
            u_lds[3][lr][lc] = e3 * inv;
            m_lds[lr][lc] = mask[(b * HH + gh) * WW + gw];
        } else {
            u_lds[0][lr][lc] = 0.0f;
            u_lds[1][lr][lc] = 0.0f;
            u_lds[2][lr][lc] = 0.0f;
            u_lds[3][lr][lc] = 0.0f;
            m_lds[lr][lc] = 0.0f;
        }
    }
    __syncthreads();

    // neighbor offsets of the 3x5 kernel, center excluded (dz-major, matches
    // the k-ordering of bilateral_filters)
    const int DZ[14] = {0,0,0,0,0, 1,1,1,1, 2,2,2,2,2};
    const int DA[14] = {0,1,2,3,4, 0,1,3,4, 0,1,2,3,4};
    float g[14];
#pragma unroll
    for (int k = 0; k < 14; ++k) {
        const float ddz = (float)(DZ[k] - 1);
        const float dda = (float)(DA[k] - 2);
        g[k] = expf(-(ddz * ddz + dda * dda) * (1.0f / (2.0f * 0.9f * 0.9f)));
    }

    // ---- Phase 2: stencil + compat epilogue, 4 pixels per thread ----
    for (int p = tid; p < TH * TW; p += 256) {
        const int r  = p >> 7;     // / TW
        const int cc = p & (TW - 1);
        const int gh = h0 + r;
        const int gw = w0 + cc;

        float ang[NCLASS]  = {0.f, 0.f, 0.f, 0.f};
        float cond[NCLASS] = {0.f, 0.f, 0.f, 0.f};
        const float mc = m_lds[r + 1][cc + 2];
        const int fpix = (b * 14 * HH + gh) * WW + gw;

#pragma unroll
        for (int k = 0; k < 14; ++k) {
            const float f  = filt[fpix + k * PLANE];
            const int lr = r + DZ[k];
            const int lc = cc + DA[k];
            const float mn = m_lds[lr][lc];
            const float fm = f * mn;
            const float gk = g[k];
#pragma unroll
            for (int c = 0; c < NCLASS; ++c) {
                const float un = u_lds[c][lr][lc];
                ang[c]  = fmaf(gk, un, ang[c]);
                cond[c] = fmaf(fm, un, cond[c]);
            }
        }

        float bi[NCLASS];
        float sa = 0.f, sb = 0.f;
#pragma unroll
        for (int c = 0; c < NCLASS; ++c) {
            bi[c] = cond[c] * mc * ang[c];   // bi_ang == ang (same theta)
            sa += ang[c];
            sb += bi[c];
        }

        const int obase = (b * NCLASS * HH + gh) * WW + gw;
#pragma unroll
        for (int c = 0; c < NCLASS; ++c) {
            const float uc = u_lds[c][r + 1][cc + 2];
            xout[obase + c * PLANE] =
                uc + 0.02f * (sa - ang[c]) + 0.1f * (sb - bi[c]);
        }
    }
}

extern "C" void kernel_launch(void* const* d_in, const int* in_sizes, int n_in,
                              void* d_out, int out_size, void* d_ws, size_t ws_size,
                              hipStream_t stream) {
    const float* x    = (const float*)d_in[0];  // [16,4,64,512]
    const float* filt = (const float*)d_in[1];  // [16,1,14,64,512]
    const float* msk  = (const float*)d_in[2];  // [16,1,64,512]
    float* out = (float*)d_out;
    float* ws0 = (float*)d_ws;                  // 8 MB intermediate

    dim3 grid(WW / TW, HH / TH, BB);            // (4, 8, 16) = 512 blocks
    dim3 block(256);

    // iter 1: x -> out ; iter 2: out -> ws0 ; iter 3: ws0 -> out
    crf_iter<<<grid, block, 0, stream>>>(x,   filt, msk, out);
    crf_iter<<<grid, block, 0, stream>>>(out, filt, msk, ws0);
    crf_iter<<<grid, block, 0, stream>>>(ws0, filt, msk, out);
}

// Round 2
// 102.451 us; speedup vs baseline: 1.0645x; 1.0645x over previous
//
#include <hip/hip_runtime.h>

// SqueezeSeg recurrent CRF, MI355X (gfx950).
// B=16, C=4, H=64, W=512, 3x5 stencil (14 neighbors), 3 iterations.
// g_ang == g_bi (same theta=0.9) -> ang == bi_ang.
// compat = (1 - I)*coef -> out[o] = coef*(sum_c v[c] - v[o]).
//
// R2: tile 4x64, 1 pixel/thread, grid 2048 blocks (8 blocks/CU vs R1's 2).
//     LDS 8.2 KB/block. Gaussian weights as compile-time literals.

#define NCLASS 4
#define HH 64
#define WW 512
#define BB 16
#define TH 4
#define TW 64
#define HALO_H (TH + 2)
#define HALO_W (TW + 4)
#define PLANE (HH * WW)

// exp(-d2 / (2*0.9^2)) for d2 = 1,2,4,5
#define G1 0.53940412f
#define G2 0.29095687f
#define G4 0.08466190f
#define G5 0.04566227f

__global__ __launch_bounds__(256, 6) void crf_iter(
    const float* __restrict__ xin,   // [B,4,H,W]
    const float* __restrict__ filt,  // [B,1,14,H,W]
    const float* __restrict__ mask,  // [B,1,H,W]
    float* __restrict__ xout)        // [B,4,H,W]
{
    __shared__ float u_lds[NCLASS][HALO_H][HALO_W];
    __shared__ float m_lds[HALO_H][HALO_W];

    const int b  = blockIdx.z;
    const int h0 = blockIdx.y * TH;
    const int w0 = blockIdx.x * TW;
    const int tid = threadIdx.x;

    // ---- Phase 1: load halo tile, softmax over class dim into LDS ----
    for (int idx = tid; idx < HALO_H * HALO_W; idx += 256) {
        const int lr = idx / HALO_W;
        const int lc = idx - lr * HALO_W;
        const int gh = h0 + lr - 1;
        const int gw = w0 + lc - 2;
        if (gh >= 0 && gh < HH && gw >= 0 && gw < WW) {
            const int base = (b * NCLASS * HH + gh) * WW + gw;
            const float v0 = xin[base + 0 * PLANE];
            const float v1 = xin[base + 1 * PLANE];
            const float v2 = xin[base + 2 * PLANE];
            const float v3 = xin[base + 3 * PLANE];
            const float mx = fmaxf(fmaxf(v0, v1), fmaxf(v2, v3));
            const float e0 = expf(v0 - mx);
            const float e1 = expf(v1 - mx);
            const float e2 = expf(v2 - mx);
            const float e3 = expf(v3 - mx);
            const float inv = 1.0f / (e0 + e1 + e2 + e3);
            u_lds[0][lr][lc] = e0 * inv;
            u_lds[1][lr][lc] = e1 * inv;
            u_lds[2][lr][lc] = e2 * inv;
            u_lds[3][lr][lc] = e3 * inv;
            m_lds[lr][lc] = mask[(b * HH + gh) * WW + gw];
        } else {
            u_lds[0][lr][lc] = 0.0f;
            u_lds[1][lr][lc] = 0.0f;
            u_lds[2][lr][lc] = 0.0f;
            u_lds[3][lr][lc] = 0.0f;
            m_lds[lr][lc] = 0.0f;
        }
    }
    __syncthreads();

    // neighbor offsets of the 3x5 kernel, center excluded (dz-major = the
    // k-ordering of bilateral_filters), with Gaussian weight literals
    const int DZ[14]   = {0,0,0,0,0, 1,1,1,1, 2,2,2,2,2};
    const int DA[14]   = {0,1,2,3,4, 0,1,3,4, 0,1,2,3,4};
    const float GW[14] = {G5,G2,G1,G2,G5, G4,G1,G1,G4, G5,G2,G1,G2,G5};

    // ---- Phase 2: stencil + compat epilogue, 1 pixel per thread ----
    const int r  = tid >> 6;          // 0..3
    const int cc = tid & 63;          // 0..63
    const int gh = h0 + r;
    const int gw = w0 + cc;

    float ang[NCLASS]  = {0.f, 0.f, 0.f, 0.f};
    float cond[NCLASS] = {0.f, 0.f, 0.f, 0.f};
    const float mc = m_lds[r + 1][cc + 2];
    const int fpix = (b * 14 * HH + gh) * WW + gw;

#pragma unroll
    for (int k = 0; k < 14; ++k) {
        const float f  = filt[fpix + k * PLANE];
        const int lr = r + DZ[k];
        const int lc = cc + DA[k];
        const float mn = m_lds[lr][lc];
        const float fm = f * mn;
        const float gk = GW[k];
#pragma unroll
        for (int c = 0; c < NCLASS; ++c) {
            const float un = u_lds[c][lr][lc];
            ang[c]  = fmaf(gk, un, ang[c]);
            cond[c] = fmaf(fm, un, cond[c]);
        }
    }

    float bi[NCLASS];
    float sa = 0.f, sb = 0.f;
#pragma unroll
    for (int c = 0; c < NCLASS; ++c) {
        bi[c] = cond[c] * mc * ang[c];   // bi_ang == ang (same theta)
        sa += ang[c];
        sb += bi[c];
    }

    const int obase = (b * NCLASS * HH + gh) * WW + gw;
#pragma unroll
    for (int c = 0; c < NCLASS; ++c) {
        const float uc = u_lds[c][r + 1][cc + 2];
        xout[obase + c * PLANE] =
            uc + 0.02f * (sa - ang[c]) + 0.1f * (sb - bi[c]);
    }
}

extern "C" void kernel_launch(void* const* d_in, const int* in_sizes, int n_in,
                              void* d_out, int out_size, void* d_ws, size_t ws_size,
                              hipStream_t stream) {
    const float* x    = (const float*)d_in[0];  // [16,4,64,512]
    const float* filt = (const float*)d_in[1];  // [16,1,14,64,512]
    const float* msk  = (const float*)d_in[2];  // [16,1,64,512]
    float* out = (float*)d_out;
    float* ws0 = (float*)d_ws;                  // 8 MB intermediate

    dim3 grid(WW / TW, HH / TH, BB);            // (8, 16, 16) = 2048 blocks
    dim3 block(256);

    // iter 1: x -> out ; iter 2: out -> ws0 ; iter 3: ws0 -> out
    crf_iter<<<grid, block, 0, stream>>>(x,   filt, msk, out);
    crf_iter<<<grid, block, 0, stream>>>(out, filt, msk, ws0);
    crf_iter<<<grid, block, 0, stream>>>(ws0, filt, msk, out);
}

// Round 4
// 98.661 us; speedup vs baseline: 1.1054x; 1.0384x over previous
//
#include <hip/hip_runtime.h>

// SqueezeSeg recurrent CRF, MI355X (gfx950). Single-kernel halo-redundant fusion:
// all 3 CRF iterations inside one block, over-computing a shrinking halo
// (12x72 -> 10x68 -> 8x64 around the owned 8x64 tile). No grid sync, no ws.
// g_ang == g_bi (theta=0.9 both) -> ang == bi_ang.
// compat = (1-I)*coef -> out[o] = coef*(sum_c v[c] - v[o]).

#define NCLASS 4
#define HH 64
#define WW 512
#define BB 16
#define TH 8
#define TW 64
#define UR (TH + 6)   // 14 rows:  tile + 3 halo each side
#define UC (TW + 12)  // 76 cols:  tile + 6 halo each side
#define PLANE (HH * WW)

// exp(-d2 / (2*0.9^2)) for d2 = 1,2,4,5
#define G1 0.53940412f
#define G2 0.29095687f
#define G4 0.08466190f
#define G5 0.04566227f

// neighbor offsets of the 3x5 kernel, center excluded, dz-major (= the
// k-ordering of bilateral_filters), relative offsets in [-1,1]x[-2,2]
#define TAPS                                                                 \
    const int   DZ[14] = {-1,-1,-1,-1,-1,  0, 0, 0, 0,  1, 1, 1, 1, 1};      \
    const int   DA[14] = {-2,-1, 0, 1, 2, -2,-1, 1, 2, -2,-1, 0, 1, 2};      \
    const float GW[14] = {G5,G2,G1,G2,G5, G4,G1,G1,G4, G5,G2,G1,G2,G5};

// MR/MC: halo margin (rows/cols) of the region this step computes.
// FINAL: write to global instead of softmax->LDS.
template <int MR, int MC, bool FINAL>
__device__ __forceinline__ void crf_step(
    float4 (*__restrict__ u_lds)[UC], const float (*__restrict__ m_lds)[UC],
    const float* __restrict__ filt, float* __restrict__ dst,
    int b, int h0, int w0, int tid)
{
    constexpr int RH = TH + 2 * MR;
    constexpr int RW = TW + 2 * MC;
    constexpr int NS = (RH * RW + 255) / 256;
    TAPS

    float4 xnew[NS];

#pragma unroll
    for (int j = 0; j < NS; ++j) {
        const int s = tid + 256 * j;
        float4 r = make_float4(0.f, 0.f, 0.f, 0.f);
        if (s < RH * RW) {
            const int lr = s / RW;
            const int lc = s - lr * RW;
            const int gh = h0 + lr - MR;
            const int gw = w0 + lc - MC;
            const int ur = lr + (3 - MR);
            const int uc = lc + (6 - MC);
            if (gh >= 0 && gh < HH && gw >= 0 && gw < WW) {
                float a0 = 0.f, a1 = 0.f, a2 = 0.f, a3 = 0.f;
                float c0 = 0.f, c1 = 0.f, c2 = 0.f, c3 = 0.f;
                const float mcen = m_lds[ur][uc];
                const float* fp = filt + ((size_t)b * 14 * HH + gh) * WW + gw;
#pragma unroll
                for (int k = 0; k < 14; ++k) {
                    const float  f  = fp[(size_t)k * PLANE];
                    const float  mn = m_lds[ur + DZ[k]][uc + DA[k]];
                    const float4 u  = u_lds[ur + DZ[k]][uc + DA[k]];
                    const float  fm = f * mn;
                    const float  gk = GW[k];
                    a0 = fmaf(gk, u.x, a0);  c0 = fmaf(fm, u.x, c0);
                    a1 = fmaf(gk, u.y, a1);  c1 = fmaf(fm, u.y, c1);
                    a2 = fmaf(gk, u.z, a2);  c2 = fmaf(fm, u.z, c2);
                    a3 = fmaf(gk, u.w, a3);  c3 = fmaf(fm, u.w, c3);
                }
                const float b0 = c0 * mcen * a0;
                const float b1 = c1 * mcen * a1;
                const float b2 = c2 * mcen * a2;
                const float b3 = c3 * mcen * a3;
                const float sa = a0 + a1 + a2 + a3;
                const float sb = b0 + b1 + b2 + b3;
                const float4 ucen = u_lds[ur][uc];
                r.x = ucen.x + 0.02f * (sa - a0) + 0.1f * (sb - b0);
                r.y = ucen.y + 0.02f * (sa - a1) + 0.1f * (sb - b1);
                r.z = ucen.z + 0.02f * (sa - a2) + 0.1f * (sb - b2);
                r.w = ucen.w + 0.02f * (sa - a3) + 0.1f * (sb - b3);
                if (!FINAL) {
                    // softmax in registers for the next iteration's unary
                    const float mx  = fmaxf(fmaxf(r.x, r.y), fmaxf(r.z, r.w));
                    const float e0  = __expf(r.x - mx);
                    const float e1  = __expf(r.y - mx);
                    const float e2  = __expf(r.z - mx);
                    const float e3  = __expf(r.w - mx);
                    const float inv = 1.0f / (e0 + e1 + e2 + e3);
                    r = make_float4(e0 * inv, e1 * inv, e2 * inv, e3 * inv);
                }
            }
            if (FINAL) {
                float* o = dst + ((size_t)b * NCLASS * HH + gh) * WW + gw;
                o[0]         = r.x;
                o[PLANE]     = r.y;
                o[2 * PLANE] = r.z;
                o[3 * PLANE] = r.w;
            }
        }
        if (!FINAL) xnew[j] = r;
    }

    if (!FINAL) {
        __syncthreads();   // all reads of u_t done before overwrite
#pragma unroll
        for (int j = 0; j < NS; ++j) {
            const int s = tid + 256 * j;
            if (s < RH * RW) {
                const int lr = s / RW;
                const int lc = s - lr * RW;
                u_lds[lr + (3 - MR)][lc + (6 - MC)] = xnew[j];
            }
        }
        __syncthreads();   // u_{t+1} visible before next step's reads
    }
}

__global__ __launch_bounds__(256, 4) void crf_fused(
    const float* __restrict__ xin,   // [B,4,H,W]
    const float* __restrict__ filt,  // [B,1,14,H,W]
    const float* __restrict__ mask,  // [B,1,H,W]
    float* __restrict__ xout)        // [B,4,H,W]
{
    __shared__ float4 u_lds[UR][UC];  // class-packed unary, 17.0 KB
    __shared__ float  m_lds[UR][UC];  // mask, 4.3 KB

    const int b   = blockIdx.z;
    const int h0  = blockIdx.y * TH;
    const int w0  = blockIdx.x * TW;
    const int tid = threadIdx.x;

    // ---- phase 0: softmax(x) + mask over the full 14x76 patch ----
    for (int idx = tid; idx < UR * UC; idx += 256) {
        const int lr = idx / UC;
        const int lc = idx - lr * UC;
        const int gh = h0 + lr - 3;
        const int gw = w0 + lc - 6;
        float4 u = make_float4(0.f, 0.f, 0.f, 0.f);
        float  m = 0.f;
        if (gh >= 0 && gh < HH && gw >= 0 && gw < WW) {
            const float* px = xin + ((size_t)b * NCLASS * HH + gh) * WW + gw;
            const float v0 = px[0];
            const float v1 = px[PLANE];
            const float v2 = px[2 * PLANE];
            const float v3 = px[3 * PLANE];
            const float mx = fmaxf(fmaxf(v0, v1), fmaxf(v2, v3));
            const float e0 = __expf(v0 - mx);
            const float e1 = __expf(v1 - mx);
            const float e2 = __expf(v2 - mx);
            const float e3 = __expf(v3 - mx);
            const float inv = 1.0f / (e0 + e1 + e2 + e3);
            u = make_float4(e0 * inv, e1 * inv, e2 * inv, e3 * inv);
            m = mask[((size_t)b * HH + gh) * WW + gw];
        }
        u_lds[lr][lc] = u;
        m_lds[lr][lc] = m;
    }
    __syncthreads();

    crf_step<2, 4, false>(u_lds, m_lds, filt, xout, b, h0, w0, tid);
    crf_step<1, 2, false>(u_lds, m_lds, filt, xout, b, h0, w0, tid);
    crf_step<0, 0, true >(u_lds, m_lds, filt, xout, b, h0, w0, tid);
}

extern "C" void kernel_launch(void* const* d_in, const int* in_sizes, int n_in,
                              void* d_out, int out_size, void* d_ws, size_t ws_size,
                              hipStream_t stream) {
    const float* x    = (const float*)d_in[0];  // [16,4,64,512]
    const float* filt = (const float*)d_in[1];  // [16,1,14,64,512]
    const float* msk  = (const float*)d_in[2];  // [16,1,64,512]
    float* out = (float*)d_out;
    (void)d_ws; (void)ws_size;

    dim3 grid(WW / TW, HH / TH, BB);   // (8, 8, 16) = 1024 blocks = 4/CU
    dim3 block(256);
    crf_fused<<<grid, block, 0, stream>>>(x, filt, msk, out);
}